// Round 1
// baseline (550.448 us; speedup 1.0000x reference)
//
#include <hip/hip_runtime.h>
#include <hip/hip_bf16.h>
#include <cstdint>

typedef __bf16 bf16x8 __attribute__((ext_vector_type(8)));
typedef float f32x4 __attribute__((ext_vector_type(4)));
typedef unsigned short u16t;

__device__ __forceinline__ u16t f2bf(float f) {
    uint32_t u = __builtin_bit_cast(uint32_t, f);
    u += 0x7FFF + ((u >> 16) & 1);
    return (u16t)(u >> 16);
}

// Problem constants
constexpr int Bb = 4, Ss = 2048, Dd = 1024, Hh = 16;
constexpr int Mrows = Bb * Ss;   // 8192
constexpr float NEG = -1e30f;

// ---------------- convert x (fp32 -> bf16) ----------------
__global__ __launch_bounds__(256) void cvt_bf16(const float* __restrict__ in,
                                                u16t* __restrict__ out, int n) {
    int i = (blockIdx.x * 256 + threadIdx.x) * 4;
    if (i >= n) return;
    float4 v = *(const float4*)(in + i);
    u16t o[4] = {f2bf(v.x), f2bf(v.y), f2bf(v.z), f2bf(v.w)};
    *(ushort4*)(out + i) = *(ushort4*)o;
}

// ---------------- transpose + convert weight: WT[n][k] = bf16(W[k][n]) ----------------
__global__ __launch_bounds__(256) void transpose_cvt(const float* __restrict__ W,
                                                     u16t* __restrict__ WT) {
    __shared__ float tile[64][65];
    int n0 = blockIdx.x * 64, k0 = blockIdx.y * 64;
    int c = threadIdx.x & 63, r0 = (threadIdx.x >> 6) * 16;
    for (int i = 0; i < 16; i++)
        tile[c][r0 + i] = W[(size_t)(k0 + r0 + i) * Dd + n0 + c];
    __syncthreads();
    for (int i = 0; i < 16; i++)
        WT[(size_t)(n0 + r0 + i) * Dd + k0 + c] = f2bf(tile[r0 + i][c]);
}

// ---------------- GEMM: C[M=8192][N=1024] = A[M][K=1024] @ BT[N][K]^T + bias ----------------
// mode 0: write bf16 to head-major (B,H,S,64) layout; mode 1: write fp32 row-major.
__global__ __launch_bounds__(256) void gemm_bt(const u16t* __restrict__ A,
                                               const u16t* __restrict__ BT,
                                               const float* __restrict__ bias,
                                               u16t* __restrict__ outBF,
                                               float* __restrict__ outF, int mode) {
    constexpr int BK = 32, LDK = 40;           // padded LDS stride (80B, 16B-aligned)
    __shared__ u16t Asm[128][LDK];
    __shared__ u16t Bsm[128][LDK];
    int tid = threadIdx.x;
    int lane = tid & 63, w = tid >> 6;
    int wm = w >> 1, wn = w & 1;
    int ln = lane & 15, g = lane >> 4;
    int m0 = blockIdx.y * 128, n0 = blockIdx.x * 128;

    f32x4 acc[4][4] = {};

    int r1 = tid >> 2, c1 = (tid & 3) * 8;     // chunk 0: rows 0..63, chunk 1: rows 64..127
    const u16t* Ap0 = A + (size_t)(m0 + r1) * Dd + c1;
    const u16t* Ap1 = A + (size_t)(m0 + r1 + 64) * Dd + c1;
    const u16t* Bp0 = BT + (size_t)(n0 + r1) * Dd + c1;
    const u16t* Bp1 = BT + (size_t)(n0 + r1 + 64) * Dd + c1;

    for (int k0 = 0; k0 < Dd; k0 += BK) {
        uint4 a0 = *(const uint4*)(Ap0 + k0);
        uint4 a1 = *(const uint4*)(Ap1 + k0);
        uint4 b0 = *(const uint4*)(Bp0 + k0);
        uint4 b1 = *(const uint4*)(Bp1 + k0);
        __syncthreads();
        *(uint4*)&Asm[r1][c1]      = a0;
        *(uint4*)&Asm[r1 + 64][c1] = a1;
        *(uint4*)&Bsm[r1][c1]      = b0;
        *(uint4*)&Bsm[r1 + 64][c1] = b1;
        __syncthreads();
        bf16x8 af[4], bf[4];
        for (int i = 0; i < 4; i++)
            af[i] = *(const bf16x8*)&Asm[wm * 64 + i * 16 + ln][g * 8];
        for (int j = 0; j < 4; j++)
            bf[j] = *(const bf16x8*)&Bsm[wn * 64 + j * 16 + ln][g * 8];
        for (int i = 0; i < 4; i++)
            for (int j = 0; j < 4; j++)
                acc[i][j] = __builtin_amdgcn_mfma_f32_16x16x32_bf16(af[i], bf[j], acc[i][j], 0, 0, 0);
    }

    for (int i = 0; i < 4; i++) {
        for (int j = 0; j < 4; j++) {
            int col = n0 + wn * 64 + j * 16 + ln;
            float bv = bias[col];
            for (int r = 0; r < 4; r++) {
                int row = m0 + wm * 64 + i * 16 + g * 4 + r;
                float v = acc[i][j][r] + bv;
                if (mode == 0) {
                    int b = row >> 11, s = row & 2047, h = col >> 6, hd = col & 63;
                    outBF[(((size_t)(b * Hh + h) << 11) + s) * 64 + hd] = f2bf(v);
                } else {
                    outF[(size_t)row * Dd + col] = v;
                }
            }
        }
    }
}

// ---------------- Flash attention: per (b,h), causal, head-major Q/K/V ----------------
__global__ __launch_bounds__(256) void attn(const u16t* __restrict__ Qh,
                                            const u16t* __restrict__ Kh,
                                            const u16t* __restrict__ Vh,
                                            u16t* __restrict__ Ob) {
    __shared__ u16t Ksm[32][72];       // padded: 144B rows
    __shared__ u16t Vts[64][40];       // transposed V: Vts[hd][kv], padded 80B rows
    __shared__ u16t Psm[4][16][40];    // per-wave P tile, padded

    int tid = threadIdx.x, lane = tid & 63, w = tid >> 6;
    int ln = lane & 15, g = lane >> 4;
    int bh = blockIdx.y;
    int qb = blockIdx.x * 64;
    int q0 = qb + w * 16;

    const u16t* Kb = Kh + (size_t)bh * Ss * 64;
    const u16t* Vb = Vh + (size_t)bh * Ss * 64;

    // Q fragments (held in registers for whole kernel)
    const u16t* Qp = Qh + ((size_t)bh * Ss + q0 + ln) * 64 + g * 8;
    bf16x8 qf[2];
    qf[0] = *(const bf16x8*)(Qp);
    qf[1] = *(const bf16x8*)(Qp + 32);

    f32x4 oacc[4] = {};
    float mrow[4], lrow[4];
    for (int r = 0; r < 4; r++) { mrow[r] = NEG; lrow[r] = 0.f; }

    int ntiles = (qb + 64) >> 5;
    int srow = tid >> 3, sc = (tid & 7) * 8;   // staging: 32 rows x 8 chunks of 8

    for (int t = 0; t < ntiles; t++) {
        int kv0 = t * 32;
        uint4 kvec = *(const uint4*)(Kb + (size_t)(kv0 + srow) * 64 + sc);
        uint4 vvec = *(const uint4*)(Vb + (size_t)(kv0 + srow) * 64 + sc);
        __syncthreads();   // previous iteration's LDS reads complete
        *(uint4*)&Ksm[srow][sc] = kvec;
        const u16t* vs = (const u16t*)&vvec;
        for (int j = 0; j < 8; j++) Vts[sc + j][srow] = vs[j];
        __syncthreads();

        // QK^T : S[16q][32kv], two 16-col sub-tiles
        f32x4 s0 = {}, s1 = {};
        for (int ks = 0; ks < 2; ks++) {
            bf16x8 b0 = *(const bf16x8*)&Ksm[ln][ks * 32 + g * 8];
            bf16x8 b1 = *(const bf16x8*)&Ksm[16 + ln][ks * 32 + g * 8];
            s0 = __builtin_amdgcn_mfma_f32_16x16x32_bf16(qf[ks], b0, s0, 0, 0, 0);
            s1 = __builtin_amdgcn_mfma_f32_16x16x32_bf16(qf[ks], b1, s1, 0, 0, 0);
        }

        // online softmax (rows distributed: row = 4g + r, cols = ln / ln+16)
        float alpha[4];
        for (int r = 0; r < 4; r++) {
            int q = q0 + g * 4 + r;
            float v0 = s0[r] * 0.125f;
            float v1 = s1[r] * 0.125f;
            if (kv0 + ln > q)      v0 = NEG;
            if (kv0 + 16 + ln > q) v1 = NEG;
            float mt = fmaxf(v0, v1);
            mt = fmaxf(mt, __shfl_xor(mt, 1));
            mt = fmaxf(mt, __shfl_xor(mt, 2));
            mt = fmaxf(mt, __shfl_xor(mt, 4));
            mt = fmaxf(mt, __shfl_xor(mt, 8));
            float mn = fmaxf(mrow[r], mt);
            float al = __expf(mrow[r] - mn);
            float p0 = __expf(v0 - mn);
            float p1 = __expf(v1 - mn);
            float rs = p0 + p1;
            rs += __shfl_xor(rs, 1);
            rs += __shfl_xor(rs, 2);
            rs += __shfl_xor(rs, 4);
            rs += __shfl_xor(rs, 8);
            lrow[r] = lrow[r] * al + rs;
            mrow[r] = mn;
            alpha[r] = al;
            Psm[w][g * 4 + r][ln]      = f2bf(p0);
            Psm[w][g * 4 + r][16 + ln] = f2bf(p1);
        }
        for (int ht = 0; ht < 4; ht++)
            for (int r = 0; r < 4; r++)
                oacc[ht][r] *= alpha[r];
        __syncthreads();   // P visible across lanes; Vts stable

        // PV : O[16q][64hd] += P[16q][32kv] @ V[32kv][64hd]
        bf16x8 pa = *(const bf16x8*)&Psm[w][ln][g * 8];
        for (int ht = 0; ht < 4; ht++) {
            bf16x8 vb = *(const bf16x8*)&Vts[ht * 16 + ln][g * 8];
            oacc[ht] = __builtin_amdgcn_mfma_f32_16x16x32_bf16(pa, vb, oacc[ht], 0, 0, 0);
        }
    }

    // epilogue: normalize and write attention output in (B,S,D) bf16
    int b = bh >> 4, h = bh & 15;
    for (int ht = 0; ht < 4; ht++) {
        for (int r = 0; r < 4; r++) {
            int q = q0 + g * 4 + r;
            float v = oacc[ht][r] / lrow[r];
            Ob[((size_t)(b * Ss + q)) * Dd + h * 64 + ht * 16 + ln] = f2bf(v);
        }
    }
}

extern "C" void kernel_launch(void* const* d_in, const int* in_sizes, int n_in,
                              void* d_out, int out_size, void* d_ws, size_t ws_size,
                              hipStream_t stream) {
    const float* x  = (const float*)d_in[0];
    const float* Wq = (const float*)d_in[1];
    const float* bq = (const float*)d_in[2];
    const float* Wk = (const float*)d_in[3];
    const float* bk = (const float*)d_in[4];
    const float* Wv = (const float*)d_in[5];
    const float* bv = (const float*)d_in[6];
    const float* Wo = (const float*)d_in[7];
    const float* bo = (const float*)d_in[8];

    char* ws = (char*)d_ws;
    size_t off = 0;
    auto alloc = [&](size_t bytes) { char* p = ws + off; off += (bytes + 255) & ~(size_t)255; return p; };
    u16t* xb  = (u16t*)alloc((size_t)Mrows * Dd * 2);
    u16t* WqT = (u16t*)alloc((size_t)Dd * Dd * 2);
    u16t* WkT = (u16t*)alloc((size_t)Dd * Dd * 2);
    u16t* WvT = (u16t*)alloc((size_t)Dd * Dd * 2);
    u16t* WoT = (u16t*)alloc((size_t)Dd * Dd * 2);
    u16t* Qh  = (u16t*)alloc((size_t)Mrows * Dd * 2);
    u16t* Kh  = (u16t*)alloc((size_t)Mrows * Dd * 2);
    u16t* Vh  = (u16t*)alloc((size_t)Mrows * Dd * 2);
    u16t* Ob  = (u16t*)alloc((size_t)Mrows * Dd * 2);

    int nx = Mrows * Dd;
    cvt_bf16<<<nx / (256 * 4), 256, 0, stream>>>(x, xb, nx);
    dim3 tg(16, 16);
    transpose_cvt<<<tg, 256, 0, stream>>>(Wq, WqT);
    transpose_cvt<<<tg, 256, 0, stream>>>(Wk, WkT);
    transpose_cvt<<<tg, 256, 0, stream>>>(Wv, WvT);
    transpose_cvt<<<tg, 256, 0, stream>>>(Wo, WoT);

    dim3 gg(Dd / 128, Mrows / 128);   // (8, 64)
    gemm_bt<<<gg, 256, 0, stream>>>(xb, WqT, bq, Qh, nullptr, 0);
    gemm_bt<<<gg, 256, 0, stream>>>(xb, WkT, bk, Kh, nullptr, 0);
    gemm_bt<<<gg, 256, 0, stream>>>(xb, WvT, bv, Vh, nullptr, 0);

    dim3 ga(Ss / 64, Bb * Hh);        // (32, 64)
    attn<<<ga, 256, 0, stream>>>(Qh, Kh, Vh, Ob);

    gemm_bt<<<gg, 256, 0, stream>>>(Ob, WoT, bo, nullptr, (float*)d_out, 1);
}

// Round 2
// 406.855 us; speedup vs baseline: 1.3529x; 1.3529x over previous
//
#include <hip/hip_runtime.h>
#include <hip/hip_bf16.h>
#include <cstdint>

typedef __bf16 bf16x8 __attribute__((ext_vector_type(8)));
typedef float f32x4 __attribute__((ext_vector_type(4)));
typedef unsigned short u16t;

__device__ __forceinline__ u16t f2bf(float f) {
    uint32_t u = __builtin_bit_cast(uint32_t, f);
    u += 0x7FFF + ((u >> 16) & 1);
    return (u16t)(u >> 16);
}

// Problem constants
constexpr int Bb = 4, Ss = 2048, Dd = 1024, Hh = 16;
constexpr int Mrows = Bb * Ss;   // 8192
constexpr float NEG = -1e30f;

// ---------------- convert x (fp32 -> bf16) ----------------
__global__ __launch_bounds__(256) void cvt_bf16(const float* __restrict__ in,
                                                u16t* __restrict__ out, int n) {
    int i = (blockIdx.x * 256 + threadIdx.x) * 4;
    if (i >= n) return;
    float4 v = *(const float4*)(in + i);
    u16t o[4] = {f2bf(v.x), f2bf(v.y), f2bf(v.z), f2bf(v.w)};
    *(ushort4*)(out + i) = *(ushort4*)o;
}

// ---------------- transpose + convert weight: WT[n][k] = bf16(W[k][n]) ----------------
__global__ __launch_bounds__(256) void transpose_cvt(const float* __restrict__ W,
                                                     u16t* __restrict__ WT) {
    __shared__ float tile[64][65];
    int n0 = blockIdx.x * 64, k0 = blockIdx.y * 64;
    int c = threadIdx.x & 63, r0 = (threadIdx.x >> 6) * 16;
    for (int i = 0; i < 16; i++)
        tile[c][r0 + i] = W[(size_t)(k0 + r0 + i) * Dd + n0 + c];
    __syncthreads();
    for (int i = 0; i < 16; i++)
        WT[(size_t)(n0 + r0 + i) * Dd + k0 + c] = f2bf(tile[r0 + i][c]);
}

// ---------------- transpose V head tiles: Vt[bh][d][s] = Vh[bh][s][d] ----------------
__global__ __launch_bounds__(256) void transpose_v(const u16t* __restrict__ Vh,
                                                   u16t* __restrict__ Vt) {
    __shared__ u16t t[64][66];
    int tid = threadIdx.x;
    int bh = blockIdx.y, s0 = blockIdx.x * 64;
    int r = tid >> 2, c = (tid & 3) * 16;
    const u16t* src = Vh + ((size_t)bh * Ss + s0 + r) * 64 + c;
    *(uint4*)&t[r][c]     = *(const uint4*)src;
    *(uint4*)&t[r][c + 8] = *(const uint4*)(src + 8);
    __syncthreads();
    u16t tmp[16];
    for (int j = 0; j < 16; j++) tmp[j] = t[c + j][r];
    u16t* dst = Vt + ((size_t)bh * 64 + r) * Ss + s0 + c;
    *(uint4*)dst       = *(uint4*)&tmp[0];
    *(uint4*)(dst + 8) = *(uint4*)&tmp[8];
}

// ---------------- GEMM: C[M=8192][N=1024] = A[M][K=1024] @ BT[N][K]^T + bias ----------------
// mode 0: write bf16 to head-major (B,H,S,64) layout (scaled); mode 1: write fp32 row-major.
__global__ __launch_bounds__(256) void gemm_bt(const u16t* __restrict__ A,
                                               const u16t* __restrict__ BT,
                                               const float* __restrict__ bias,
                                               u16t* __restrict__ outBF,
                                               float* __restrict__ outF, int mode,
                                               float oscale) {
    constexpr int BK = 32, LDK = 40;           // padded LDS stride
    __shared__ u16t Asm[128][LDK];
    __shared__ u16t Bsm[128][LDK];
    int tid = threadIdx.x;
    int lane = tid & 63, w = tid >> 6;
    int wm = w >> 1, wn = w & 1;
    int ln = lane & 15, g = lane >> 4;
    int m0 = blockIdx.y * 128, n0 = blockIdx.x * 128;

    f32x4 acc[4][4] = {};

    int r1 = tid >> 2, c1 = (tid & 3) * 8;
    const u16t* Ap0 = A + (size_t)(m0 + r1) * Dd + c1;
    const u16t* Ap1 = A + (size_t)(m0 + r1 + 64) * Dd + c1;
    const u16t* Bp0 = BT + (size_t)(n0 + r1) * Dd + c1;
    const u16t* Bp1 = BT + (size_t)(n0 + r1 + 64) * Dd + c1;

    for (int k0 = 0; k0 < Dd; k0 += BK) {
        uint4 a0 = *(const uint4*)(Ap0 + k0);
        uint4 a1 = *(const uint4*)(Ap1 + k0);
        uint4 b0 = *(const uint4*)(Bp0 + k0);
        uint4 b1 = *(const uint4*)(Bp1 + k0);
        __syncthreads();
        *(uint4*)&Asm[r1][c1]      = a0;
        *(uint4*)&Asm[r1 + 64][c1] = a1;
        *(uint4*)&Bsm[r1][c1]      = b0;
        *(uint4*)&Bsm[r1 + 64][c1] = b1;
        __syncthreads();
        bf16x8 af[4], bf[4];
        for (int i = 0; i < 4; i++)
            af[i] = *(const bf16x8*)&Asm[wm * 64 + i * 16 + ln][g * 8];
        for (int j = 0; j < 4; j++)
            bf[j] = *(const bf16x8*)&Bsm[wn * 64 + j * 16 + ln][g * 8];
        for (int i = 0; i < 4; i++)
            for (int j = 0; j < 4; j++)
                acc[i][j] = __builtin_amdgcn_mfma_f32_16x16x32_bf16(af[i], bf[j], acc[i][j], 0, 0, 0);
    }

    for (int i = 0; i < 4; i++) {
        for (int j = 0; j < 4; j++) {
            int col = n0 + wn * 64 + j * 16 + ln;
            float bv = bias[col];
            for (int r = 0; r < 4; r++) {
                int row = m0 + wm * 64 + i * 16 + g * 4 + r;
                float v = (acc[i][j][r] + bv) * oscale;
                if (mode == 0) {
                    int b = row >> 11, s = row & 2047, h = col >> 6, hd = col & 63;
                    outBF[(((size_t)(b * Hh + h) << 11) + s) * 64 + hd] = f2bf(v);
                } else {
                    outF[(size_t)row * Dd + col] = v;
                }
            }
        }
    }
}

// ---------------- Flash attention ----------------
// 128 q rows/block, 4 waves x 32 rows, KV tile = 64, double-buffered K / V^T in LDS.
__global__ __launch_bounds__(256, 2) void attn(const u16t* __restrict__ Qh,
                                               const u16t* __restrict__ Kh,
                                               const u16t* __restrict__ Vt,
                                               u16t* __restrict__ Ob) {
    __shared__ u16t Ksm[2][64][72];
    __shared__ u16t Vsm[2][64][72];   // V^T tile: [d=64][kv=64]
    __shared__ u16t Psm[4][32][72];   // per-wave P tile

    int tid = threadIdx.x, lane = tid & 63, w = tid >> 6;
    int ln = lane & 15, g = lane >> 4;
    int bh = blockIdx.y;
    int qb = blockIdx.x * 128;
    int q0 = qb + w * 32;

    const u16t* Kb = Kh + (size_t)bh * Ss * 64;
    const u16t* Vb = Vt + (size_t)bh * 64 * Ss;

    // Q fragments in registers (scale 1/8 folded into Q projection)
    bf16x8 qf[2][2];
    for (int mi = 0; mi < 2; mi++) {
        const u16t* Qp = Qh + ((size_t)bh * Ss + q0 + mi * 16 + ln) * 64 + g * 8;
        qf[mi][0] = *(const bf16x8*)Qp;
        qf[mi][1] = *(const bf16x8*)(Qp + 32);
    }

    f32x4 oacc[2][4] = {};
    float mrow[2][4], lrow[2][4];
    for (int mi = 0; mi < 2; mi++)
        for (int r = 0; r < 4; r++) { mrow[mi][r] = NEG; lrow[mi][r] = 0.f; }

    int nt = (qb >> 6) + 2;
    int sr = tid >> 2, sc = (tid & 3) * 16;
    const u16t* Kp = Kb + (size_t)sr * 64 + sc;   // K rows (kv), 64 elems
    const u16t* Vp = Vb + (size_t)sr * Ss + sc;   // V^T rows (d), cols kv

    // prologue: stage tile 0 into buffer 0
    {
        uint4 k0 = *(const uint4*)Kp;
        uint4 k1 = *(const uint4*)(Kp + 8);
        uint4 v0 = *(const uint4*)Vp;
        uint4 v1 = *(const uint4*)(Vp + 8);
        *(uint4*)&Ksm[0][sr][sc]     = k0;
        *(uint4*)&Ksm[0][sr][sc + 8] = k1;
        *(uint4*)&Vsm[0][sr][sc]     = v0;
        *(uint4*)&Vsm[0][sr][sc + 8] = v1;
    }
    __syncthreads();

    for (int t = 0; t < nt; t++) {
        int cur = t & 1;
        int kv0 = t << 6;
        bool pre = (t + 1 < nt);
        uint4 k0, k1, v0, v1;
        if (pre) {
            const u16t* kp = Kp + (size_t)(kv0 + 64) * 64;
            k0 = *(const uint4*)kp;
            k1 = *(const uint4*)(kp + 8);
            const u16t* vp = Vp + kv0 + 64;
            v0 = *(const uint4*)vp;
            v1 = *(const uint4*)(vp + 8);
        }
        bool active = (kv0 <= q0 + 31);
        if (active) {
            // ---- QK^T : S[32q][64kv] per wave ----
            f32x4 s[2][4] = {};
            for (int j = 0; j < 4; j++) {
                bf16x8 b0 = *(const bf16x8*)&Ksm[cur][j * 16 + ln][g * 8];
                bf16x8 b1 = *(const bf16x8*)&Ksm[cur][j * 16 + ln][32 + g * 8];
                for (int mi = 0; mi < 2; mi++) {
                    s[mi][j] = __builtin_amdgcn_mfma_f32_16x16x32_bf16(qf[mi][0], b0, s[mi][j], 0, 0, 0);
                    s[mi][j] = __builtin_amdgcn_mfma_f32_16x16x32_bf16(qf[mi][1], b1, s[mi][j], 0, 0, 0);
                }
            }
            // ---- online softmax ----
            for (int mi = 0; mi < 2; mi++) {
                bool needmask = (kv0 + 63 > q0 + mi * 16);
                for (int r = 0; r < 4; r++) {
                    int q = q0 + mi * 16 + g * 4 + r;
                    float v[4];
                    for (int j = 0; j < 4; j++) v[j] = s[mi][j][r];
                    if (needmask)
                        for (int j = 0; j < 4; j++)
                            if (kv0 + j * 16 + ln > q) v[j] = NEG;
                    float mt = fmaxf(fmaxf(v[0], v[1]), fmaxf(v[2], v[3]));
                    mt = fmaxf(mt, __shfl_xor(mt, 1));
                    mt = fmaxf(mt, __shfl_xor(mt, 2));
                    mt = fmaxf(mt, __shfl_xor(mt, 4));
                    mt = fmaxf(mt, __shfl_xor(mt, 8));
                    float mn = fmaxf(mrow[mi][r], mt);
                    float al = __expf(mrow[mi][r] - mn);
                    float p0 = __expf(v[0] - mn);
                    float p1 = __expf(v[1] - mn);
                    float p2 = __expf(v[2] - mn);
                    float p3 = __expf(v[3] - mn);
                    float rs = (p0 + p1) + (p2 + p3);
                    rs += __shfl_xor(rs, 1);
                    rs += __shfl_xor(rs, 2);
                    rs += __shfl_xor(rs, 4);
                    rs += __shfl_xor(rs, 8);
                    lrow[mi][r] = lrow[mi][r] * al + rs;
                    mrow[mi][r] = mn;
                    for (int ht = 0; ht < 4; ht++) oacc[mi][ht][r] *= al;
                    int prow = mi * 16 + g * 4 + r;
                    Psm[w][prow][ln]      = f2bf(p0);
                    Psm[w][prow][16 + ln] = f2bf(p1);
                    Psm[w][prow][32 + ln] = f2bf(p2);
                    Psm[w][prow][48 + ln] = f2bf(p3);
                }
            }
        }
        // stage next tile into the other buffer (safe: its readers hit last barrier)
        if (pre) {
            *(uint4*)&Ksm[cur ^ 1][sr][sc]     = k0;
            *(uint4*)&Ksm[cur ^ 1][sr][sc + 8] = k1;
            *(uint4*)&Vsm[cur ^ 1][sr][sc]     = v0;
            *(uint4*)&Vsm[cur ^ 1][sr][sc + 8] = v1;
        }
        if (active) {
            // ---- PV : O[32q][64d] += P[32q][64kv] @ V[64kv][64d] ----
            bf16x8 vb0[4], vb1[4];
            for (int ht = 0; ht < 4; ht++) {
                vb0[ht] = *(const bf16x8*)&Vsm[cur][ht * 16 + ln][g * 8];
                vb1[ht] = *(const bf16x8*)&Vsm[cur][ht * 16 + ln][32 + g * 8];
            }
            for (int mi = 0; mi < 2; mi++) {
                bf16x8 pa0 = *(const bf16x8*)&Psm[w][mi * 16 + ln][g * 8];
                bf16x8 pa1 = *(const bf16x8*)&Psm[w][mi * 16 + ln][32 + g * 8];
                for (int ht = 0; ht < 4; ht++) {
                    oacc[mi][ht] = __builtin_amdgcn_mfma_f32_16x16x32_bf16(pa0, vb0[ht], oacc[mi][ht], 0, 0, 0);
                    oacc[mi][ht] = __builtin_amdgcn_mfma_f32_16x16x32_bf16(pa1, vb1[ht], oacc[mi][ht], 0, 0, 0);
                }
            }
        }
        __syncthreads();
    }

    // epilogue: normalize, write (B,S,D) bf16
    int b = bh >> 4, h = bh & 15;
    for (int mi = 0; mi < 2; mi++) {
        for (int ht = 0; ht < 4; ht++) {
            for (int r = 0; r < 4; r++) {
                int q = q0 + mi * 16 + g * 4 + r;
                float vv = oacc[mi][ht][r] / lrow[mi][r];
                Ob[((size_t)(b * Ss + q)) * Dd + h * 64 + ht * 16 + ln] = f2bf(vv);
            }
        }
    }
}

extern "C" void kernel_launch(void* const* d_in, const int* in_sizes, int n_in,
                              void* d_out, int out_size, void* d_ws, size_t ws_size,
                              hipStream_t stream) {
    const float* x  = (const float*)d_in[0];
    const float* Wq = (const float*)d_in[1];
    const float* bq = (const float*)d_in[2];
    const float* Wk = (const float*)d_in[3];
    const float* bk = (const float*)d_in[4];
    const float* Wv = (const float*)d_in[5];
    const float* bv = (const float*)d_in[6];
    const float* Wo = (const float*)d_in[7];
    const float* bo = (const float*)d_in[8];

    char* ws = (char*)d_ws;
    size_t off = 0;
    auto alloc = [&](size_t bytes) { char* p = ws + off; off += (bytes + 255) & ~(size_t)255; return p; };
    u16t* xb  = (u16t*)alloc((size_t)Mrows * Dd * 2);
    u16t* WqT = (u16t*)alloc((size_t)Dd * Dd * 2);
    u16t* WkT = (u16t*)alloc((size_t)Dd * Dd * 2);
    u16t* WvT = (u16t*)alloc((size_t)Dd * Dd * 2);
    u16t* WoT = (u16t*)alloc((size_t)Dd * Dd * 2);
    u16t* Qh  = (u16t*)alloc((size_t)Mrows * Dd * 2);
    u16t* Kh  = (u16t*)alloc((size_t)Mrows * Dd * 2);
    u16t* Vh  = (u16t*)alloc((size_t)Mrows * Dd * 2);   // V head-major, then reused as attn out
    u16t* Vtp = (u16t*)alloc((size_t)Mrows * Dd * 2);   // V^T per head

    int nx = Mrows * Dd;
    cvt_bf16<<<nx / (256 * 4), 256, 0, stream>>>(x, xb, nx);
    dim3 tg(16, 16);
    transpose_cvt<<<tg, 256, 0, stream>>>(Wq, WqT);
    transpose_cvt<<<tg, 256, 0, stream>>>(Wk, WkT);
    transpose_cvt<<<tg, 256, 0, stream>>>(Wv, WvT);
    transpose_cvt<<<tg, 256, 0, stream>>>(Wo, WoT);

    dim3 gg(Dd / 128, Mrows / 128);   // (8, 64)
    gemm_bt<<<gg, 256, 0, stream>>>(xb, WqT, bq, Qh, nullptr, 0, 0.125f);
    gemm_bt<<<gg, 256, 0, stream>>>(xb, WkT, bk, Kh, nullptr, 0, 1.0f);
    gemm_bt<<<gg, 256, 0, stream>>>(xb, WvT, bv, Vh, nullptr, 0, 1.0f);

    dim3 gv(Ss / 64, Bb * Hh);        // (32, 64)
    transpose_v<<<gv, 256, 0, stream>>>(Vh, Vtp);

    u16t* Ob = Vh;                    // reuse V head-major buffer for attention output
    dim3 ga(Ss / 128, Bb * Hh);       // (16, 64)
    attn<<<ga, 256, 0, stream>>>(Qh, Kh, Vtp, Ob);

    gemm_bt<<<gg, 256, 0, stream>>>(Ob, WoT, bo, nullptr, (float*)d_out, 1, 1.0f);
}

// Round 3
// 255.590 us; speedup vs baseline: 2.1536x; 1.5918x over previous
//
#include <hip/hip_runtime.h>
#include <hip/hip_bf16.h>
#include <cstdint>

typedef __bf16 bf16x8 __attribute__((ext_vector_type(8)));
typedef float f32x4 __attribute__((ext_vector_type(4)));
typedef float f32x16 __attribute__((ext_vector_type(16)));
typedef unsigned short u16t;

__device__ __forceinline__ u16t f2bf(float f) {
    uint32_t u = __builtin_bit_cast(uint32_t, f);
    u += 0x7FFF + ((u >> 16) & 1);
    return (u16t)(u >> 16);
}

// Problem constants
constexpr int Bb = 4, Ss = 2048, Dd = 1024, Hh = 16;
constexpr int Mrows = Bb * Ss;   // 8192
constexpr float NEG = -1e30f;

// ---------------- convert x (fp32 -> bf16) ----------------
__global__ __launch_bounds__(256) void cvt_bf16(const float* __restrict__ in,
                                                u16t* __restrict__ out, int n) {
    int i = (blockIdx.x * 256 + threadIdx.x) * 4;
    if (i >= n) return;
    float4 v = *(const float4*)(in + i);
    u16t o[4] = {f2bf(v.x), f2bf(v.y), f2bf(v.z), f2bf(v.w)};
    *(ushort4*)(out + i) = *(ushort4*)o;
}

// ---------------- transpose + convert weight: WT[n][k] = bf16(W[k][n]) ----------------
__global__ __launch_bounds__(256) void transpose_cvt(const float* __restrict__ W,
                                                     u16t* __restrict__ WT) {
    __shared__ float tile[64][65];
    int n0 = blockIdx.x * 64, k0 = blockIdx.y * 64;
    int c = threadIdx.x & 63, r0 = (threadIdx.x >> 6) * 16;
    for (int i = 0; i < 16; i++)
        tile[c][r0 + i] = W[(size_t)(k0 + r0 + i) * Dd + n0 + c];
    __syncthreads();
    for (int i = 0; i < 16; i++)
        WT[(size_t)(n0 + r0 + i) * Dd + k0 + c] = f2bf(tile[r0 + i][c]);
}

// ---------------- GEMM: C[M=8192][N=1024] = A[M][K=1024] @ BT[N][K]^T + bias ----------------
// mode 0: bf16 head-major (B,H,S,64); mode 1: fp32 row-major; mode 2: bf16 V^T (bh,64,Ss).
__global__ __launch_bounds__(256) void gemm_bt(const u16t* __restrict__ A,
                                               const u16t* __restrict__ BT,
                                               const float* __restrict__ bias,
                                               u16t* __restrict__ outBF,
                                               float* __restrict__ outF, int mode,
                                               float oscale) {
    constexpr int BK = 32, LDK = 40;           // padded LDS stride
    __shared__ u16t Asm[128][LDK];
    __shared__ u16t Bsm[128][LDK];
    int tid = threadIdx.x;
    int lane = tid & 63, w = tid >> 6;
    int wm = w >> 1, wn = w & 1;
    int ln = lane & 15, g = lane >> 4;
    int m0 = blockIdx.y * 128, n0 = blockIdx.x * 128;

    f32x4 acc[4][4] = {};

    int r1 = tid >> 2, c1 = (tid & 3) * 8;
    const u16t* Ap0 = A + (size_t)(m0 + r1) * Dd + c1;
    const u16t* Ap1 = A + (size_t)(m0 + r1 + 64) * Dd + c1;
    const u16t* Bp0 = BT + (size_t)(n0 + r1) * Dd + c1;
    const u16t* Bp1 = BT + (size_t)(n0 + r1 + 64) * Dd + c1;

    for (int k0 = 0; k0 < Dd; k0 += BK) {
        uint4 a0 = *(const uint4*)(Ap0 + k0);
        uint4 a1 = *(const uint4*)(Ap1 + k0);
        uint4 b0 = *(const uint4*)(Bp0 + k0);
        uint4 b1 = *(const uint4*)(Bp1 + k0);
        __syncthreads();
        *(uint4*)&Asm[r1][c1]      = a0;
        *(uint4*)&Asm[r1 + 64][c1] = a1;
        *(uint4*)&Bsm[r1][c1]      = b0;
        *(uint4*)&Bsm[r1 + 64][c1] = b1;
        __syncthreads();
        bf16x8 af[4], bf[4];
        for (int i = 0; i < 4; i++)
            af[i] = *(const bf16x8*)&Asm[wm * 64 + i * 16 + ln][g * 8];
        for (int j = 0; j < 4; j++)
            bf[j] = *(const bf16x8*)&Bsm[wn * 64 + j * 16 + ln][g * 8];
        for (int i = 0; i < 4; i++)
            for (int j = 0; j < 4; j++)
                acc[i][j] = __builtin_amdgcn_mfma_f32_16x16x32_bf16(af[i], bf[j], acc[i][j], 0, 0, 0);
    }

    for (int i = 0; i < 4; i++) {
        for (int j = 0; j < 4; j++) {
            int col = n0 + wn * 64 + j * 16 + ln;
            float bv = bias[col];
            int rowb = m0 + wm * 64 + i * 16 + g * 4;
            if (mode == 0) {
                for (int r = 0; r < 4; r++) {
                    int row = rowb + r;
                    float v = (acc[i][j][r] + bv) * oscale;
                    int b = row >> 11, s = row & 2047, h = col >> 6, hd = col & 63;
                    outBF[(((size_t)(b * Hh + h) << 11) + s) * 64 + hd] = f2bf(v);
                }
            } else if (mode == 1) {
                for (int r = 0; r < 4; r++) {
                    float v = acc[i][j][r] + bv;
                    outF[(size_t)(rowb + r) * Dd + col] = v;
                }
            } else {
                // V^T: out[(b*16+h)*64+hd][s], 4 consecutive s values -> 8B store
                u16t pk4[4];
                for (int r = 0; r < 4; r++) pk4[r] = f2bf(acc[i][j][r] + bv);
                int b = rowb >> 11, s = rowb & 2047, h = col >> 6, hd = col & 63;
                *(ushort4*)(outBF + ((size_t)((b * Hh + h) * 64 + hd) << 11) + s) = *(ushort4*)pk4;
            }
        }
    }
}

// ---------------- Flash attention, swapped-QK^T in-register softmax ----------------
// 4 waves x 32 q rows = 128 q/block. KVBLK = 64, double-buffered K and V^T in LDS
// via global_load_lds (linear dest, inverse-swizzled source, XOR-swizzled reads).
__global__ __launch_bounds__(256) void attn(const u16t* __restrict__ Qh,
                                            const u16t* __restrict__ Kh,
                                            const u16t* __restrict__ Vt,
                                            u16t* __restrict__ Ob) {
    __shared__ __align__(16) u16t Ksm[2][64 * 64];
    __shared__ __align__(16) u16t Vsm[2][64 * 64];

    int tid = threadIdx.x, lane = tid & 63, w = tid >> 6;
    int l31 = lane & 31, hi = lane >> 5;
    int bh = blockIdx.y;
    int qx = blockIdx.x;
    if ((bh >> 4) & 1) qx = 15 - qx;          // cross-CU causal load balance
    int qb = qx * 128;
    int q0w = qb + w * 32;
    int qlane = q0w + l31;

    const u16t* Kb = Kh + (size_t)bh * Ss * 64;
    const u16t* Vb = Vt + (size_t)bh * 64 * Ss;

    // Q B-fragments: qB[ks][j] = Q[qlane][16ks + hi*8 + j]
    bf16x8 qB[4];
    {
        const u16t* Qp = Qh + ((size_t)bh * Ss + qlane) * 64 + hi * 8;
        #pragma unroll
        for (int ks = 0; ks < 4; ks++)
            qB[ks] = *(const bf16x8*)(Qp + 16 * ks);
    }

    f32x16 oacc[2] = {};
    float m_run = NEG, l_run = 0.f;

    int nt = (qb >> 6) + 2;

    // staging geometry: wave w, issue i covers LDS rows 8*(2w+i)..+7 linearly;
    // lane l -> row base+(l>>3), chunk (l&7); source chunk pre-swizzled: (l&7)^(r&7)
    int sr0 = w * 16 + (lane >> 3);
    int sr1 = sr0 + 8;
    int sc0 = ((lane & 7) ^ (sr0 & 7)) * 8;
    int sc1 = ((lane & 7) ^ (sr1 & 7)) * 8;
    const u16t* Kg0 = Kb + (size_t)sr0 * 64 + sc0;
    const u16t* Kg1 = Kb + (size_t)sr1 * 64 + sc1;
    const u16t* Vg0 = Vb + (size_t)sr0 * Ss + sc0;
    const u16t* Vg1 = Vb + (size_t)sr1 * Ss + sc1;

    auto stage = [&](int buf, int t) {
        size_t koff = (size_t)t * 64 * 64;     // kv0 rows into K
        size_t voff = (size_t)t * 64;          // kv0 cols into V^T
        __builtin_amdgcn_global_load_lds(Kg0 + koff, &Ksm[buf][(w * 2 + 0) * 512], 16, 0, 0);
        __builtin_amdgcn_global_load_lds(Kg1 + koff, &Ksm[buf][(w * 2 + 1) * 512], 16, 0, 0);
        __builtin_amdgcn_global_load_lds(Vg0 + voff, &Vsm[buf][(w * 2 + 0) * 512], 16, 0, 0);
        __builtin_amdgcn_global_load_lds(Vg1 + voff, &Vsm[buf][(w * 2 + 1) * 512], 16, 0, 0);
    };

    stage(0, 0);
    __syncthreads();

    int rs7 = l31 & 7;   // row-swizzle key for A-frag reads (rows l31 and 32+l31 share &7)

    for (int t = 0; t < nt; t++) {
        int cur = t & 1;
        int kv0 = t << 6;
        if (t + 1 < nt) stage(cur ^ 1, t + 1);

        bool active = (kv0 <= q0w + 31);
        if (active) {
            // ---- QK^T (swapped): p[ti] = S^T[32ti + kvloc][qlane] ----
            f32x16 p0 = {}, p1 = {};
            __builtin_amdgcn_s_setprio(1);
            #pragma unroll
            for (int ks = 0; ks < 4; ks++) {
                int cc = (2 * ks + hi) ^ rs7;
                bf16x8 ka0 = *(const bf16x8*)&Ksm[cur][(size_t)l31 * 64 + cc * 8];
                bf16x8 ka1 = *(const bf16x8*)&Ksm[cur][(size_t)(32 + l31) * 64 + cc * 8];
                p0 = __builtin_amdgcn_mfma_f32_32x32x16_bf16(ka0, qB[ks], p0, 0, 0, 0);
                p1 = __builtin_amdgcn_mfma_f32_32x32x16_bf16(ka1, qB[ks], p1, 0, 0, 0);
            }
            __builtin_amdgcn_s_setprio(0);

            float pv[32];
            #pragma unroll
            for (int r = 0; r < 16; r++) { pv[r] = p0[r]; pv[16 + r] = p1[r]; }

            // causal mask (diagonal tile only)
            if (kv0 + 63 > q0w) {
                #pragma unroll
                for (int ti = 0; ti < 2; ti++)
                    #pragma unroll
                    for (int r = 0; r < 16; r++) {
                        int kvg = kv0 + 32 * ti + (r & 3) + 8 * (r >> 2) + 4 * hi;
                        if (kvg > qlane) pv[16 * ti + r] = NEG;
                    }
            }

            // ---- online softmax (exp2 domain), lane-local + one cross-half shfl ----
            float mt = pv[0];
            #pragma unroll
            for (int r = 1; r < 32; r++) mt = fmaxf(mt, pv[r]);
            mt = fmaxf(mt, __shfl_xor(mt, 32));
            float mn = fmaxf(m_run, mt);
            float al = __builtin_exp2f(m_run - mn);
            m_run = mn;
            float rsum = 0.f;
            #pragma unroll
            for (int r = 0; r < 32; r++) { pv[r] = __builtin_exp2f(pv[r] - mn); rsum += pv[r]; }
            rsum += __shfl_xor(rsum, 32);
            l_run = l_run * al + rsum;
            #pragma unroll
            for (int r = 0; r < 16; r++) { oacc[0][r] *= al; oacc[1][r] *= al; }

            // ---- pack P -> PV B-fragments: 16 cvt_pk + 8 permlane32_swap ----
            bf16x8 pb[4];
            #pragma unroll
            for (int half = 0; half < 2; half++) {
                const int base = 16 * half;
                uint32_t c0, c1, c2, c3;
                asm("v_cvt_pk_bf16_f32 %0, %1, %2" : "=v"(c0) : "v"(pv[base + 0]), "v"(pv[base + 1]));
                asm("v_cvt_pk_bf16_f32 %0, %1, %2" : "=v"(c1) : "v"(pv[base + 2]), "v"(pv[base + 3]));
                asm("v_cvt_pk_bf16_f32 %0, %1, %2" : "=v"(c2) : "v"(pv[base + 4]), "v"(pv[base + 5]));
                asm("v_cvt_pk_bf16_f32 %0, %1, %2" : "=v"(c3) : "v"(pv[base + 6]), "v"(pv[base + 7]));
                asm volatile("v_permlane32_swap_b32 %0, %1" : "+v"(c0), "+v"(c2));
                asm volatile("v_permlane32_swap_b32 %0, %1" : "+v"(c1), "+v"(c3));
                uint32_t w4[4] = {c0, c1, c2, c3};
                pb[2 * half] = *(bf16x8*)w4;
                uint32_t d0, d1, d2, d3;
                asm("v_cvt_pk_bf16_f32 %0, %1, %2" : "=v"(d0) : "v"(pv[base + 8]),  "v"(pv[base + 9]));
                asm("v_cvt_pk_bf16_f32 %0, %1, %2" : "=v"(d1) : "v"(pv[base + 10]), "v"(pv[base + 11]));
                asm("v_cvt_pk_bf16_f32 %0, %1, %2" : "=v"(d2) : "v"(pv[base + 12]), "v"(pv[base + 13]));
                asm("v_cvt_pk_bf16_f32 %0, %1, %2" : "=v"(d3) : "v"(pv[base + 14]), "v"(pv[base + 15]));
                asm volatile("v_permlane32_swap_b32 %0, %1" : "+v"(d0), "+v"(d2));
                asm volatile("v_permlane32_swap_b32 %0, %1" : "+v"(d1), "+v"(d3));
                uint32_t w5[4] = {d0, d1, d2, d3};
                pb[2 * half + 1] = *(bf16x8*)w5;
            }

            // ---- PV (swapped): O^T[d][q] += V^T[d][kv] @ P^T[kv][q] ----
            __builtin_amdgcn_s_setprio(1);
            #pragma unroll
            for (int dt = 0; dt < 2; dt++) {
                int drow = dt * 32 + l31;
                #pragma unroll
                for (int ks = 0; ks < 4; ks++) {
                    int cc = (2 * ks + hi) ^ rs7;
                    bf16x8 va = *(const bf16x8*)&Vsm[cur][(size_t)drow * 64 + cc * 8];
                    oacc[dt] = __builtin_amdgcn_mfma_f32_32x32x16_bf16(va, pb[ks], oacc[dt], 0, 0, 0);
                }
            }
            __builtin_amdgcn_s_setprio(0);
        }
        __syncthreads();
    }

    // ---- epilogue: normalize (lane-scalar), write (B,S,D) bf16 ----
    float inv = 1.0f / l_run;
    int b = bh >> 4, h = bh & 15;
    u16t* Op = Ob + ((size_t)(b * Ss + qlane)) * Dd + h * 64;
    #pragma unroll
    for (int dt = 0; dt < 2; dt++)
        #pragma unroll
        for (int rq = 0; rq < 4; rq++) {
            u16t pk4[4];
            #pragma unroll
            for (int j = 0; j < 4; j++) pk4[j] = f2bf(oacc[dt][rq * 4 + j] * inv);
            int d0 = dt * 32 + rq * 8 + hi * 4;
            *(ushort4*)(Op + d0) = *(ushort4*)pk4;
        }
}

extern "C" void kernel_launch(void* const* d_in, const int* in_sizes, int n_in,
                              void* d_out, int out_size, void* d_ws, size_t ws_size,
                              hipStream_t stream) {
    const float* x  = (const float*)d_in[0];
    const float* Wq = (const float*)d_in[1];
    const float* bq = (const float*)d_in[2];
    const float* Wk = (const float*)d_in[3];
    const float* bk = (const float*)d_in[4];
    const float* Wv = (const float*)d_in[5];
    const float* bv = (const float*)d_in[6];
    const float* Wo = (const float*)d_in[7];
    const float* bo = (const float*)d_in[8];

    char* ws = (char*)d_ws;
    size_t off = 0;
    auto alloc = [&](size_t bytes) { char* p = ws + off; off += (bytes + 255) & ~(size_t)255; return p; };
    u16t* xb  = (u16t*)alloc((size_t)Mrows * Dd * 2);
    u16t* WqT = (u16t*)alloc((size_t)Dd * Dd * 2);
    u16t* WkT = (u16t*)alloc((size_t)Dd * Dd * 2);
    u16t* WvT = (u16t*)alloc((size_t)Dd * Dd * 2);
    u16t* WoT = (u16t*)alloc((size_t)Dd * Dd * 2);
    u16t* Qh  = (u16t*)alloc((size_t)Mrows * Dd * 2);
    u16t* Kh  = (u16t*)alloc((size_t)Mrows * Dd * 2);
    u16t* Vtp = (u16t*)alloc((size_t)Mrows * Dd * 2);   // V^T per head
    u16t* Ob  = (u16t*)alloc((size_t)Mrows * Dd * 2);

    int nx = Mrows * Dd;
    cvt_bf16<<<nx / (256 * 4), 256, 0, stream>>>(x, xb, nx);
    dim3 tg(16, 16);
    transpose_cvt<<<tg, 256, 0, stream>>>(Wq, WqT);
    transpose_cvt<<<tg, 256, 0, stream>>>(Wk, WkT);
    transpose_cvt<<<tg, 256, 0, stream>>>(Wv, WvT);
    transpose_cvt<<<tg, 256, 0, stream>>>(Wo, WoT);

    constexpr float QSCALE = 0.125f * 1.44269504088896340736f;  // 1/sqrt(64) * log2(e)
    dim3 gg(Dd / 128, Mrows / 128);   // (8, 64)
    gemm_bt<<<gg, 256, 0, stream>>>(xb, WqT, bq, Qh, nullptr, 0, QSCALE);
    gemm_bt<<<gg, 256, 0, stream>>>(xb, WkT, bk, Kh, nullptr, 0, 1.0f);
    gemm_bt<<<gg, 256, 0, stream>>>(xb, WvT, bv, Vtp, nullptr, 2, 1.0f);

    dim3 ga(Ss / 128, Bb * Hh);       // (16, 64)
    attn<<<ga, 256, 0, stream>>>(Qh, Kh, Vtp, Ob);

    gemm_bt<<<gg, 256, 0, stream>>>(Ob, WoT, bo, nullptr, (float*)d_out, 1, 1.0f);
}

// Round 4
// 235.722 us; speedup vs baseline: 2.3352x; 1.0843x over previous
//
#include <hip/hip_runtime.h>
#include <hip/hip_bf16.h>
#include <cstdint>

typedef __bf16 bf16x8 __attribute__((ext_vector_type(8)));
typedef float f32x4 __attribute__((ext_vector_type(4)));
typedef float f32x16 __attribute__((ext_vector_type(16)));
typedef unsigned short u16t;

__device__ __forceinline__ u16t f2bf(float f) {
    uint32_t u = __builtin_bit_cast(uint32_t, f);
    u += 0x7FFF + ((u >> 16) & 1);
    return (u16t)(u >> 16);
}

// Problem constants
constexpr int Bb = 4, Ss = 2048, Dd = 1024, Hh = 16;
constexpr int Mrows = Bb * Ss;   // 8192
constexpr float NEG = -1e30f;

// ---------------- convert x (fp32 -> bf16) ----------------
__global__ __launch_bounds__(256) void cvt_bf16(const float* __restrict__ in,
                                                u16t* __restrict__ out, int n) {
    int i = (blockIdx.x * 256 + threadIdx.x) * 4;
    if (i >= n) return;
    float4 v = *(const float4*)(in + i);
    u16t o[4] = {f2bf(v.x), f2bf(v.y), f2bf(v.z), f2bf(v.w)};
    *(ushort4*)(out + i) = *(ushort4*)o;
}

// ---------------- transpose + convert all 4 weights: WT[n][k] = bf16(W[k][n]) ----------------
__global__ __launch_bounds__(256) void transpose_cvt4(const float* __restrict__ W0, u16t* __restrict__ T0,
                                                      const float* __restrict__ W1, u16t* __restrict__ T1,
                                                      const float* __restrict__ W2, u16t* __restrict__ T2,
                                                      const float* __restrict__ W3, u16t* __restrict__ T3) {
    __shared__ float tile[64][65];
    const float* W = blockIdx.z == 0 ? W0 : blockIdx.z == 1 ? W1 : blockIdx.z == 2 ? W2 : W3;
    u16t* WT       = blockIdx.z == 0 ? T0 : blockIdx.z == 1 ? T1 : blockIdx.z == 2 ? T2 : T3;
    int n0 = blockIdx.x * 64, k0 = blockIdx.y * 64;
    int c = threadIdx.x & 63, r0 = (threadIdx.x >> 6) * 16;
    for (int i = 0; i < 16; i++)
        tile[c][r0 + i] = W[(size_t)(k0 + r0 + i) * Dd + n0 + c];
    __syncthreads();
    for (int i = 0; i < 16; i++)
        WT[(size_t)(n0 + r0 + i) * Dd + k0 + c] = f2bf(tile[r0 + i][c]);
}

// ---------------- GEMM (m97 structure): C = A @ BT^T + bias ----------------
// global_load_lds staging, linear [128][32] LDS, chunk swizzled by (row&3).
// mode 0: bf16 head-major (B,H,S,64); mode 1: fp32 row-major; mode 2: bf16 V^T (bh,64,Ss).
__global__ __launch_bounds__(256) void gemm_bt(const u16t* __restrict__ A,
                                               const u16t* __restrict__ BT,
                                               const float* __restrict__ bias,
                                               u16t* __restrict__ outBF,
                                               float* __restrict__ outF, int mode,
                                               float oscale) {
    __shared__ __align__(16) u16t Asm[128 * 32];
    __shared__ __align__(16) u16t Bsm[128 * 32];
    int tid = threadIdx.x, lane = tid & 63, w = tid >> 6;
    int wm = w >> 1, wn = w & 1;
    int ln = lane & 15, g = lane >> 4;
    int m0 = blockIdx.y * 128, n0 = blockIdx.x * 128;

    f32x4 acc[4][4] = {};

    // staging: wave w covers rows w*32 .. w*32+31 in two 16-row issues.
    // LDS slot (r, c) holds src[r][c ^ (r&3)]  (chunks of 8 elems = 16B)
    int sr = w * 32 + (lane >> 2);
    int sc = (((lane & 3) ^ (sr & 3)) * 8);
    const u16t* Ag0 = A + (size_t)(m0 + sr) * Dd + sc;
    const u16t* Ag1 = A + (size_t)(m0 + sr + 16) * Dd + sc;
    const u16t* Bg0 = BT + (size_t)(n0 + sr) * Dd + sc;
    const u16t* Bg1 = BT + (size_t)(n0 + sr + 16) * Dd + sc;
    u16t* As0 = &Asm[(w * 32) * 32];
    u16t* As1 = &Asm[(w * 32 + 16) * 32];
    u16t* Bs0 = &Bsm[(w * 32) * 32];
    u16t* Bs1 = &Bsm[(w * 32 + 16) * 32];

    for (int k0 = 0; k0 < Dd; k0 += 32) {
        __syncthreads();
        __builtin_amdgcn_global_load_lds(Ag0 + k0, As0, 16, 0, 0);
        __builtin_amdgcn_global_load_lds(Ag1 + k0, As1, 16, 0, 0);
        __builtin_amdgcn_global_load_lds(Bg0 + k0, Bs0, 16, 0, 0);
        __builtin_amdgcn_global_load_lds(Bg1 + k0, Bs1, 16, 0, 0);
        __syncthreads();
        bf16x8 af[4], bf[4];
        #pragma unroll
        for (int i = 0; i < 4; i++) {
            int row = wm * 64 + i * 16 + ln;
            af[i] = *(const bf16x8*)&Asm[row * 32 + ((g ^ (row & 3)) * 8)];
        }
        #pragma unroll
        for (int j = 0; j < 4; j++) {
            int row = wn * 64 + j * 16 + ln;
            bf[j] = *(const bf16x8*)&Bsm[row * 32 + ((g ^ (row & 3)) * 8)];
        }
        #pragma unroll
        for (int i = 0; i < 4; i++)
            #pragma unroll
            for (int j = 0; j < 4; j++)
                acc[i][j] = __builtin_amdgcn_mfma_f32_16x16x32_bf16(af[i], bf[j], acc[i][j], 0, 0, 0);
    }

    #pragma unroll
    for (int i = 0; i < 4; i++) {
        #pragma unroll
        for (int j = 0; j < 4; j++) {
            int col = n0 + wn * 64 + j * 16 + ln;
            float bv = bias[col];
            int rowb = m0 + wm * 64 + i * 16 + g * 4;
            if (mode == 0) {
                for (int r = 0; r < 4; r++) {
                    int row = rowb + r;
                    float v = (acc[i][j][r] + bv) * oscale;
                    int b = row >> 11, s = row & 2047, h = col >> 6, hd = col & 63;
                    outBF[(((size_t)(b * Hh + h) << 11) + s) * 64 + hd] = f2bf(v);
                }
            } else if (mode == 1) {
                for (int r = 0; r < 4; r++)
                    outF[(size_t)(rowb + r) * Dd + col] = acc[i][j][r] + bv;
            } else {
                u16t pk4[4];
                for (int r = 0; r < 4; r++) pk4[r] = f2bf(acc[i][j][r] + bv);
                int b = rowb >> 11, s = rowb & 2047, h = col >> 6, hd = col & 63;
                *(ushort4*)(outBF + ((size_t)((b * Hh + h) * 64 + hd) << 11) + s) = *(ushort4*)pk4;
            }
        }
    }
}

// ---------------- Flash attention, swapped-QK^T in-register softmax ----------------
__global__ __launch_bounds__(256) void attn(const u16t* __restrict__ Qh,
                                            const u16t* __restrict__ Kh,
                                            const u16t* __restrict__ Vt,
                                            u16t* __restrict__ Ob) {
    __shared__ __align__(16) u16t Ksm[2][64 * 64];
    __shared__ __align__(16) u16t Vsm[2][64 * 64];

    int tid = threadIdx.x, lane = tid & 63, w = tid >> 6;
    int l31 = lane & 31, hi = lane >> 5;
    int bh = blockIdx.y;
    int qx = blockIdx.x;
    if ((bh >> 4) & 1) qx = 15 - qx;          // cross-CU causal load balance
    int qb = qx * 128;
    int q0w = qb + w * 32;
    int qlane = q0w + l31;

    const u16t* Kb = Kh + (size_t)bh * Ss * 64;
    const u16t* Vb = Vt + (size_t)bh * 64 * Ss;

    bf16x8 qB[4];
    {
        const u16t* Qp = Qh + ((size_t)bh * Ss + qlane) * 64 + hi * 8;
        #pragma unroll
        for (int ks = 0; ks < 4; ks++)
            qB[ks] = *(const bf16x8*)(Qp + 16 * ks);
    }

    f32x16 oacc[2] = {};
    float m_run = NEG, l_run = 0.f;

    int nt = (qb >> 6) + 2;

    // staging: issue i of wave w covers LDS rows w*16+i*8 .. +7 linearly.
    // slot (r, c) holds src[r][c ^ swz(r)], swz(r) = (r&7) ^ ((r>>3)&3)
    int sr0 = w * 16 + (lane >> 3);
    int sr1 = sr0 + 8;
    int sc0 = (((lane & 7) ^ (sr0 & 7) ^ ((sr0 >> 3) & 3)) * 8);
    int sc1 = (((lane & 7) ^ (sr1 & 7) ^ ((sr1 >> 3) & 3)) * 8);
    const u16t* Kg0 = Kb + (size_t)sr0 * 64 + sc0;
    const u16t* Kg1 = Kb + (size_t)sr1 * 64 + sc1;
    const u16t* Vg0 = Vb + (size_t)sr0 * Ss + sc0;
    const u16t* Vg1 = Vb + (size_t)sr1 * Ss + sc1;

    auto stage = [&](int buf, int t) {
        size_t koff = (size_t)t * 64 * 64;
        size_t voff = (size_t)t * 64;
        __builtin_amdgcn_global_load_lds(Kg0 + koff, &Ksm[buf][(w * 2 + 0) * 512], 16, 0, 0);
        __builtin_amdgcn_global_load_lds(Kg1 + koff, &Ksm[buf][(w * 2 + 1) * 512], 16, 0, 0);
        __builtin_amdgcn_global_load_lds(Vg0 + voff, &Vsm[buf][(w * 2 + 0) * 512], 16, 0, 0);
        __builtin_amdgcn_global_load_lds(Vg1 + voff, &Vsm[buf][(w * 2 + 1) * 512], 16, 0, 0);
    };

    stage(0, 0);
    __syncthreads();

    int swzr = (l31 & 7) ^ ((l31 >> 3) & 3);   // same key for rows l31, 32+l31

    for (int t = 0; t < nt; t++) {
        int cur = t & 1;
        int kv0 = t << 6;
        if (t + 1 < nt) stage(cur ^ 1, t + 1);

        bool active = (kv0 <= q0w + 31);
        if (active) {
            // ---- QK^T (swapped): lane owns one q-column of S^T ----
            f32x16 p0 = {}, p1 = {};
            __builtin_amdgcn_s_setprio(1);
            #pragma unroll
            for (int ks = 0; ks < 4; ks++) {
                int cc = (2 * ks + hi) ^ swzr;
                bf16x8 ka0 = *(const bf16x8*)&Ksm[cur][(size_t)l31 * 64 + cc * 8];
                bf16x8 ka1 = *(const bf16x8*)&Ksm[cur][(size_t)(32 + l31) * 64 + cc * 8];
                p0 = __builtin_amdgcn_mfma_f32_32x32x16_bf16(ka0, qB[ks], p0, 0, 0, 0);
                p1 = __builtin_amdgcn_mfma_f32_32x32x16_bf16(ka1, qB[ks], p1, 0, 0, 0);
            }
            __builtin_amdgcn_s_setprio(0);

            float pv[32];
            #pragma unroll
            for (int r = 0; r < 16; r++) { pv[r] = p0[r]; pv[16 + r] = p1[r]; }

            if (kv0 + 63 > q0w) {               // causal mask, diagonal tiles only
                #pragma unroll
                for (int ti = 0; ti < 2; ti++)
                    #pragma unroll
                    for (int r = 0; r < 16; r++) {
                        int kvg = kv0 + 32 * ti + (r & 3) + 8 * (r >> 2) + 4 * hi;
                        if (kvg > qlane) pv[16 * ti + r] = NEG;
                    }
            }

            // ---- online softmax, defer-max (THR=10 in exp2 domain) ----
            float mt = fmaxf(pv[0], pv[1]);
            #pragma unroll
            for (int r = 2; r < 32; r += 2)
                mt = fmaxf(fmaxf(mt, pv[r]), pv[r + 1]);
            mt = fmaxf(mt, __shfl_xor(mt, 32));
            if (__any(mt > m_run + 10.0f)) {
                float mn = fmaxf(m_run, mt);
                float al = __builtin_exp2f(m_run - mn);
                m_run = mn;
                l_run *= al;
                #pragma unroll
                for (int r = 0; r < 16; r++) { oacc[0][r] *= al; oacc[1][r] *= al; }
            }
            #pragma unroll
            for (int r = 0; r < 32; r++) pv[r] = __builtin_exp2f(pv[r] - m_run);
            float sa = 0.f, sb = 0.f, sc_ = 0.f, sd = 0.f;
            #pragma unroll
            for (int r = 0; r < 32; r += 4) {
                sa += pv[r]; sb += pv[r + 1]; sc_ += pv[r + 2]; sd += pv[r + 3];
            }
            float rsum = (sa + sb) + (sc_ + sd);
            rsum += __shfl_xor(rsum, 32);
            l_run += rsum;

            // ---- pack P -> PV B-fragments: 16 cvt_pk + 8 permlane32_swap ----
            bf16x8 pb[4];
            #pragma unroll
            for (int half = 0; half < 2; half++) {
                const int base = 16 * half;
                uint32_t c0, c1, c2, c3;
                asm("v_cvt_pk_bf16_f32 %0, %1, %2" : "=v"(c0) : "v"(pv[base + 0]), "v"(pv[base + 1]));
                asm("v_cvt_pk_bf16_f32 %0, %1, %2" : "=v"(c1) : "v"(pv[base + 2]), "v"(pv[base + 3]));
                asm("v_cvt_pk_bf16_f32 %0, %1, %2" : "=v"(c2) : "v"(pv[base + 4]), "v"(pv[base + 5]));
                asm("v_cvt_pk_bf16_f32 %0, %1, %2" : "=v"(c3) : "v"(pv[base + 6]), "v"(pv[base + 7]));
                asm volatile("v_permlane32_swap_b32 %0, %1" : "+v"(c0), "+v"(c2));
                asm volatile("v_permlane32_swap_b32 %0, %1" : "+v"(c1), "+v"(c3));
                uint32_t w4[4] = {c0, c1, c2, c3};
                pb[2 * half] = *(bf16x8*)w4;
                uint32_t d0, d1, d2, d3;
                asm("v_cvt_pk_bf16_f32 %0, %1, %2" : "=v"(d0) : "v"(pv[base + 8]),  "v"(pv[base + 9]));
                asm("v_cvt_pk_bf16_f32 %0, %1, %2" : "=v"(d1) : "v"(pv[base + 10]), "v"(pv[base + 11]));
                asm("v_cvt_pk_bf16_f32 %0, %1, %2" : "=v"(d2) : "v"(pv[base + 12]), "v"(pv[base + 13]));
                asm("v_cvt_pk_bf16_f32 %0, %1, %2" : "=v"(d3) : "v"(pv[base + 14]), "v"(pv[base + 15]));
                asm volatile("v_permlane32_swap_b32 %0, %1" : "+v"(d0), "+v"(d2));
                asm volatile("v_permlane32_swap_b32 %0, %1" : "+v"(d1), "+v"(d3));
                uint32_t w5[4] = {d0, d1, d2, d3};
                pb[2 * half + 1] = *(bf16x8*)w5;
            }

            // ---- PV (swapped): O^T[d][q] += V^T[d][kv] @ P^T[kv][q] ----
            __builtin_amdgcn_s_setprio(1);
            #pragma unroll
            for (int dt = 0; dt < 2; dt++) {
                int drow = dt * 32 + l31;
                #pragma unroll
                for (int ks = 0; ks < 4; ks++) {
                    int cc = (2 * ks + hi) ^ swzr;
                    bf16x8 va = *(const bf16x8*)&Vsm[cur][(size_t)drow * 64 + cc * 8];
                    oacc[dt] = __builtin_amdgcn_mfma_f32_32x32x16_bf16(va, pb[ks], oacc[dt], 0, 0, 0);
                }
            }
            __builtin_amdgcn_s_setprio(0);
        }
        __syncthreads();
    }

    // ---- epilogue ----
    float inv = 1.0f / l_run;
    int b = bh >> 4, h = bh & 15;
    u16t* Op = Ob + ((size_t)(b * Ss + qlane)) * Dd + h * 64;
    #pragma unroll
    for (int dt = 0; dt < 2; dt++)
        #pragma unroll
        for (int rq = 0; rq < 4; rq++) {
            u16t pk4[4];
            #pragma unroll
            for (int j = 0; j < 4; j++) pk4[j] = f2bf(oacc[dt][rq * 4 + j] * inv);
            int d0 = dt * 32 + rq * 8 + hi * 4;
            *(ushort4*)(Op + d0) = *(ushort4*)pk4;
        }
}

extern "C" void kernel_launch(void* const* d_in, const int* in_sizes, int n_in,
                              void* d_out, int out_size, void* d_ws, size_t ws_size,
                              hipStream_t stream) {
    const float* x  = (const float*)d_in[0];
    const float* Wq = (const float*)d_in[1];
    const float* bq = (const float*)d_in[2];
    const float* Wk = (const float*)d_in[3];
    const float* bk = (const float*)d_in[4];
    const float* Wv = (const float*)d_in[5];
    const float* bv = (const float*)d_in[6];
    const float* Wo = (const float*)d_in[7];
    const float* bo = (const float*)d_in[8];

    char* ws = (char*)d_ws;
    size_t off = 0;
    auto alloc = [&](size_t bytes) { char* p = ws + off; off += (bytes + 255) & ~(size_t)255; return p; };
    u16t* xb  = (u16t*)alloc((size_t)Mrows * Dd * 2);
    u16t* WqT = (u16t*)alloc((size_t)Dd * Dd * 2);
    u16t* WkT = (u16t*)alloc((size_t)Dd * Dd * 2);
    u16t* WvT = (u16t*)alloc((size_t)Dd * Dd * 2);
    u16t* WoT = (u16t*)alloc((size_t)Dd * Dd * 2);
    u16t* Qh  = (u16t*)alloc((size_t)Mrows * Dd * 2);
    u16t* Kh  = (u16t*)alloc((size_t)Mrows * Dd * 2);
    u16t* Vtp = (u16t*)alloc((size_t)Mrows * Dd * 2);
    u16t* Ob  = (u16t*)alloc((size_t)Mrows * Dd * 2);

    int nx = Mrows * Dd;
    cvt_bf16<<<nx / (256 * 4), 256, 0, stream>>>(x, xb, nx);
    dim3 tg(16, 16, 4);
    transpose_cvt4<<<tg, 256, 0, stream>>>(Wq, WqT, Wk, WkT, Wv, WvT, Wo, WoT);

    constexpr float QSCALE = 0.125f * 1.44269504088896340736f;  // 1/sqrt(64) * log2(e)
    dim3 gg(Dd / 128, Mrows / 128);   // (8, 64)
    gemm_bt<<<gg, 256, 0, stream>>>(xb, WqT, bq, Qh, nullptr, 0, QSCALE);
    gemm_bt<<<gg, 256, 0, stream>>>(xb, WkT, bk, Kh, nullptr, 0, 1.0f);
    gemm_bt<<<gg, 256, 0, stream>>>(xb, WvT, bv, Vtp, nullptr, 2, 1.0f);

    dim3 ga(Ss / 128, Bb * Hh);       // (16, 64)
    attn<<<ga, 256, 0, stream>>>(Qh, Kh, Vtp, Ob);

    gemm_bt<<<gg, 256, 0, stream>>>(Ob, WoT, bo, nullptr, (float*)d_out, 1, 1.0f);
}

// Round 5
// 205.981 us; speedup vs baseline: 2.6723x; 1.1444x over previous
//
#include <hip/hip_runtime.h>
#include <hip/hip_bf16.h>
#include <cstdint>

typedef __bf16 bf16x8 __attribute__((ext_vector_type(8)));
typedef float f32x4 __attribute__((ext_vector_type(4)));
typedef float f32x16 __attribute__((ext_vector_type(16)));
typedef unsigned short u16t;

__device__ __forceinline__ u16t f2bf(float f) {
    uint32_t u = __builtin_bit_cast(uint32_t, f);
    u += 0x7FFF + ((u >> 16) & 1);
    return (u16t)(u >> 16);
}

// Problem constants
constexpr int Bb = 4, Ss = 2048, Dd = 1024, Hh = 16;
constexpr int Mrows = Bb * Ss;   // 8192
constexpr float NEG = -1e30f;
constexpr float QSCALE = 0.125f * 1.44269504088896340736f;  // 1/sqrt(64) * log2(e)

// ---------------- convert x (fp32 -> bf16) ----------------
__global__ __launch_bounds__(256) void cvt_bf16(const float* __restrict__ in,
                                                u16t* __restrict__ out, int n) {
    int i = (blockIdx.x * 256 + threadIdx.x) * 4;
    if (i >= n) return;
    float4 v = *(const float4*)(in + i);
    u16t o[4] = {f2bf(v.x), f2bf(v.y), f2bf(v.z), f2bf(v.w)};
    *(ushort4*)(out + i) = *(ushort4*)o;
}

// -------- transpose + convert weights: Wq/Wk/Wv -> concatenated [3072][1024], Wo -> [1024][1024] --------
__global__ __launch_bounds__(256) void transpose_cvt4(const float* __restrict__ W0,
                                                      const float* __restrict__ W1,
                                                      const float* __restrict__ W2,
                                                      const float* __restrict__ W3,
                                                      u16t* __restrict__ Tqkv,
                                                      u16t* __restrict__ To) {
    __shared__ float tile[64][65];
    int z = blockIdx.z;
    const float* W = z == 0 ? W0 : z == 1 ? W1 : z == 2 ? W2 : W3;
    u16t* WT = z < 3 ? Tqkv + (size_t)z * Dd * Dd : To;
    int n0 = blockIdx.x * 64, k0 = blockIdx.y * 64;
    int c = threadIdx.x & 63, r0 = (threadIdx.x >> 6) * 16;
    for (int i = 0; i < 16; i++)
        tile[c][r0 + i] = W[(size_t)(k0 + r0 + i) * Dd + n0 + c];
    __syncthreads();
    for (int i = 0; i < 16; i++)
        WT[(size_t)(n0 + r0 + i) * Dd + k0 + c] = f2bf(tile[r0 + i][c]);
}

// ---------------- fused QKV GEMM: [8192 x 3072] = x @ WqkvT^T, segmented epilogue ----------------
__global__ __launch_bounds__(256) void gemm_qkv(const u16t* __restrict__ A,
                                                const u16t* __restrict__ BT,
                                                const float* __restrict__ bq,
                                                const float* __restrict__ bk,
                                                const float* __restrict__ bvv,
                                                u16t* __restrict__ Qh,
                                                u16t* __restrict__ Kh,
                                                u16t* __restrict__ Vt) {
    __shared__ __align__(16) u16t Asm[128 * 32];
    __shared__ __align__(16) u16t Bsm[128 * 32];
    int tid = threadIdx.x, lane = tid & 63, w = tid >> 6;
    int wm = w >> 1, wn = w & 1;
    int ln = lane & 15, g = lane >> 4;
    // XCD-aware swizzle: 1536 blocks, 8 XCDs, 192 contiguous tiles per XCD
    int bid = blockIdx.x;
    int wg = (bid & 7) * 192 + (bid >> 3);
    int n0 = (wg % 24) * 128, m0 = (wg / 24) * 128;

    f32x4 acc[4][4] = {};

    int sr = w * 32 + (lane >> 2);
    int sc = (((lane & 3) ^ (sr & 3)) * 8);
    const u16t* Ag0 = A + (size_t)(m0 + sr) * Dd + sc;
    const u16t* Ag1 = A + (size_t)(m0 + sr + 16) * Dd + sc;
    const u16t* Bg0 = BT + (size_t)(n0 + sr) * Dd + sc;
    const u16t* Bg1 = BT + (size_t)(n0 + sr + 16) * Dd + sc;
    u16t* As0 = &Asm[(w * 32) * 32];
    u16t* As1 = &Asm[(w * 32 + 16) * 32];
    u16t* Bs0 = &Bsm[(w * 32) * 32];
    u16t* Bs1 = &Bsm[(w * 32 + 16) * 32];

    for (int k0 = 0; k0 < Dd; k0 += 32) {
        __syncthreads();
        __builtin_amdgcn_global_load_lds(Ag0 + k0, As0, 16, 0, 0);
        __builtin_amdgcn_global_load_lds(Ag1 + k0, As1, 16, 0, 0);
        __builtin_amdgcn_global_load_lds(Bg0 + k0, Bs0, 16, 0, 0);
        __builtin_amdgcn_global_load_lds(Bg1 + k0, Bs1, 16, 0, 0);
        __syncthreads();
        bf16x8 af[4], bf[4];
        #pragma unroll
        for (int i = 0; i < 4; i++) {
            int row = wm * 64 + i * 16 + ln;
            af[i] = *(const bf16x8*)&Asm[row * 32 + ((g ^ (row & 3)) * 8)];
        }
        #pragma unroll
        for (int j = 0; j < 4; j++) {
            int row = wn * 64 + j * 16 + ln;
            bf[j] = *(const bf16x8*)&Bsm[row * 32 + ((g ^ (row & 3)) * 8)];
        }
        #pragma unroll
        for (int i = 0; i < 4; i++)
            #pragma unroll
            for (int j = 0; j < 4; j++)
                acc[i][j] = __builtin_amdgcn_mfma_f32_16x16x32_bf16(af[i], bf[j], acc[i][j], 0, 0, 0);
    }

    #pragma unroll
    for (int i = 0; i < 4; i++) {
        #pragma unroll
        for (int j = 0; j < 4; j++) {
            int col = n0 + wn * 64 + j * 16 + ln;
            int seg = col >> 10, c1k = col & 1023;
            float bias = seg == 0 ? bq[c1k] : seg == 1 ? bk[c1k] : bvv[c1k];
            int rowb = m0 + wm * 64 + i * 16 + g * 4;
            int b = rowb >> 11, s = rowb & 2047, h = c1k >> 6, hd = c1k & 63;
            if (seg == 0) {
                for (int r = 0; r < 4; r++) {
                    float v = (acc[i][j][r] + bias) * QSCALE;
                    Qh[((size_t)(b * Hh + h) * Ss + s + r) * 64 + hd] = f2bf(v);
                }
            } else if (seg == 1) {
                for (int r = 0; r < 4; r++)
                    Kh[((size_t)(b * Hh + h) * Ss + s + r) * 64 + hd] = f2bf(acc[i][j][r] + bias);
            } else {
                u16t pk4[4];
                for (int r = 0; r < 4; r++) pk4[r] = f2bf(acc[i][j][r] + bias);
                *(ushort4*)(Vt + ((size_t)((b * Hh + h) * 64 + hd) << 11) + s) = *(ushort4*)pk4;
            }
        }
    }
}

// ---------------- output GEMM: d_out[8192 x 1024] fp32 ----------------
__global__ __launch_bounds__(256) void gemm_o(const u16t* __restrict__ A,
                                              const u16t* __restrict__ BT,
                                              const float* __restrict__ bias,
                                              float* __restrict__ outF) {
    __shared__ __align__(16) u16t Asm[128 * 32];
    __shared__ __align__(16) u16t Bsm[128 * 32];
    int tid = threadIdx.x, lane = tid & 63, w = tid >> 6;
    int wm = w >> 1, wn = w & 1;
    int ln = lane & 15, g = lane >> 4;
    int bid = blockIdx.x;                       // 512 blocks
    int wg = (bid & 7) * 64 + (bid >> 3);
    int n0 = (wg & 7) * 128, m0 = (wg >> 3) * 128;

    f32x4 acc[4][4] = {};

    int sr = w * 32 + (lane >> 2);
    int sc = (((lane & 3) ^ (sr & 3)) * 8);
    const u16t* Ag0 = A + (size_t)(m0 + sr) * Dd + sc;
    const u16t* Ag1 = A + (size_t)(m0 + sr + 16) * Dd + sc;
    const u16t* Bg0 = BT + (size_t)(n0 + sr) * Dd + sc;
    const u16t* Bg1 = BT + (size_t)(n0 + sr + 16) * Dd + sc;
    u16t* As0 = &Asm[(w * 32) * 32];
    u16t* As1 = &Asm[(w * 32 + 16) * 32];
    u16t* Bs0 = &Bsm[(w * 32) * 32];
    u16t* Bs1 = &Bsm[(w * 32 + 16) * 32];

    for (int k0 = 0; k0 < Dd; k0 += 32) {
        __syncthreads();
        __builtin_amdgcn_global_load_lds(Ag0 + k0, As0, 16, 0, 0);
        __builtin_amdgcn_global_load_lds(Ag1 + k0, As1, 16, 0, 0);
        __builtin_amdgcn_global_load_lds(Bg0 + k0, Bs0, 16, 0, 0);
        __builtin_amdgcn_global_load_lds(Bg1 + k0, Bs1, 16, 0, 0);
        __syncthreads();
        bf16x8 af[4], bf[4];
        #pragma unroll
        for (int i = 0; i < 4; i++) {
            int row = wm * 64 + i * 16 + ln;
            af[i] = *(const bf16x8*)&Asm[row * 32 + ((g ^ (row & 3)) * 8)];
        }
        #pragma unroll
        for (int j = 0; j < 4; j++) {
            int row = wn * 64 + j * 16 + ln;
            bf[j] = *(const bf16x8*)&Bsm[row * 32 + ((g ^ (row & 3)) * 8)];
        }
        #pragma unroll
        for (int i = 0; i < 4; i++)
            #pragma unroll
            for (int j = 0; j < 4; j++)
                acc[i][j] = __builtin_amdgcn_mfma_f32_16x16x32_bf16(af[i], bf[j], acc[i][j], 0, 0, 0);
    }

    #pragma unroll
    for (int i = 0; i < 4; i++) {
        #pragma unroll
        for (int j = 0; j < 4; j++) {
            int col = n0 + wn * 64 + j * 16 + ln;
            float bv = bias[col];
            int rowb = m0 + wm * 64 + i * 16 + g * 4;
            for (int r = 0; r < 4; r++)
                outF[(size_t)(rowb + r) * Dd + col] = acc[i][j][r] + bv;
        }
    }
}

// ---------------- Flash attention, swapped-QK^T, balanced q-tile pairs ----------------
// Each block processes q-tiles qx and 15-qx sequentially -> uniform 34 kv-tiles/block.
__global__ __launch_bounds__(256) void attn(const u16t* __restrict__ Qh,
                                            const u16t* __restrict__ Kh,
                                            const u16t* __restrict__ Vt,
                                            u16t* __restrict__ Ob) {
    __shared__ __align__(16) u16t Ksm[2][64 * 64];
    __shared__ __align__(16) u16t Vsm[2][64 * 64];

    int tid = threadIdx.x, lane = tid & 63, w = tid >> 6;
    int l31 = lane & 31, hi = lane >> 5;
    int bh = blockIdx.y;

    const u16t* Kb = Kh + (size_t)bh * Ss * 64;
    const u16t* Vb = Vt + (size_t)bh * 64 * Ss;

    // staging geometry: issue i of wave w covers LDS rows w*16+i*8 .. +7 linearly.
    // slot (r, c) holds src[r][c ^ swz(r)], swz(r) = (r&7) ^ ((r>>3)&3)
    int sr0 = w * 16 + (lane >> 3);
    int sr1 = sr0 + 8;
    int sc0 = (((lane & 7) ^ (sr0 & 7) ^ ((sr0 >> 3) & 3)) * 8);
    int sc1 = (((lane & 7) ^ (sr1 & 7) ^ ((sr1 >> 3) & 3)) * 8);
    const u16t* Kg0 = Kb + (size_t)sr0 * 64 + sc0;
    const u16t* Kg1 = Kb + (size_t)sr1 * 64 + sc1;
    const u16t* Vg0 = Vb + (size_t)sr0 * Ss + sc0;
    const u16t* Vg1 = Vb + (size_t)sr1 * Ss + sc1;

    auto stage = [&](int buf, int t) {
        size_t koff = (size_t)t * 64 * 64;
        size_t voff = (size_t)t * 64;
        __builtin_amdgcn_global_load_lds(Kg0 + koff, &Ksm[buf][(w * 2 + 0) * 512], 16, 0, 0);
        __builtin_amdgcn_global_load_lds(Kg1 + koff, &Ksm[buf][(w * 2 + 1) * 512], 16, 0, 0);
        __builtin_amdgcn_global_load_lds(Vg0 + voff, &Vsm[buf][(w * 2 + 0) * 512], 16, 0, 0);
        __builtin_amdgcn_global_load_lds(Vg1 + voff, &Vsm[buf][(w * 2 + 1) * 512], 16, 0, 0);
    };

    int swzr = (l31 & 7) ^ ((l31 >> 3) & 3);   // same key for rows l31, 32+l31

    for (int task = 0; task < 2; task++) {
        int qx = task == 0 ? (int)blockIdx.x : 15 - (int)blockIdx.x;
        int qb = qx * 128;
        int q0w = qb + w * 32;
        int qlane = q0w + l31;

        bf16x8 qB[4];
        {
            const u16t* Qp = Qh + ((size_t)bh * Ss + qlane) * 64 + hi * 8;
            #pragma unroll
            for (int ks = 0; ks < 4; ks++)
                qB[ks] = *(const bf16x8*)(Qp + 16 * ks);
        }

        f32x16 oacc[2] = {};
        float m_run = NEG, l_run = 0.f;
        int nt = (qb >> 6) + 2;

        stage(0, 0);
        __syncthreads();

        for (int t = 0; t < nt; t++) {
            int cur = t & 1;
            int kv0 = t << 6;
            if (t + 1 < nt) stage(cur ^ 1, t + 1);

            bool active = (kv0 <= q0w + 31);
            if (active) {
                // ---- QK^T (swapped): lane owns one q-column of S^T ----
                f32x16 p0 = {}, p1 = {};
                __builtin_amdgcn_s_setprio(1);
                #pragma unroll
                for (int ks = 0; ks < 4; ks++) {
                    int cc = (2 * ks + hi) ^ swzr;
                    bf16x8 ka0 = *(const bf16x8*)&Ksm[cur][(size_t)l31 * 64 + cc * 8];
                    bf16x8 ka1 = *(const bf16x8*)&Ksm[cur][(size_t)(32 + l31) * 64 + cc * 8];
                    p0 = __builtin_amdgcn_mfma_f32_32x32x16_bf16(ka0, qB[ks], p0, 0, 0, 0);
                    p1 = __builtin_amdgcn_mfma_f32_32x32x16_bf16(ka1, qB[ks], p1, 0, 0, 0);
                }
                __builtin_amdgcn_s_setprio(0);

                float pv[32];
                #pragma unroll
                for (int r = 0; r < 16; r++) { pv[r] = p0[r]; pv[16 + r] = p1[r]; }

                if (kv0 + 63 > q0w) {               // causal mask, diagonal tiles only
                    #pragma unroll
                    for (int ti = 0; ti < 2; ti++)
                        #pragma unroll
                        for (int r = 0; r < 16; r++) {
                            int kvg = kv0 + 32 * ti + (r & 3) + 8 * (r >> 2) + 4 * hi;
                            if (kvg > qlane) pv[16 * ti + r] = NEG;
                        }
                }

                // ---- online softmax, defer-max (THR=10, exp2 domain) ----
                float mt = fmaxf(pv[0], pv[1]);
                #pragma unroll
                for (int r = 2; r < 32; r += 2)
                    mt = fmaxf(fmaxf(mt, pv[r]), pv[r + 1]);
                mt = fmaxf(mt, __shfl_xor(mt, 32));
                if (__any(mt > m_run + 10.0f)) {
                    float mn = fmaxf(m_run, mt);
                    float al = __builtin_exp2f(m_run - mn);
                    m_run = mn;
                    l_run *= al;
                    #pragma unroll
                    for (int r = 0; r < 16; r++) { oacc[0][r] *= al; oacc[1][r] *= al; }
                }
                #pragma unroll
                for (int r = 0; r < 32; r++) pv[r] = __builtin_exp2f(pv[r] - m_run);
                float sa = 0.f, sb = 0.f, sc_ = 0.f, sd = 0.f;
                #pragma unroll
                for (int r = 0; r < 32; r += 4) {
                    sa += pv[r]; sb += pv[r + 1]; sc_ += pv[r + 2]; sd += pv[r + 3];
                }
                float rsum = (sa + sb) + (sc_ + sd);
                rsum += __shfl_xor(rsum, 32);
                l_run += rsum;

                // ---- pack P -> PV B-fragments: 16 cvt_pk + 8 permlane32_swap ----
                bf16x8 pb[4];
                #pragma unroll
                for (int half = 0; half < 2; half++) {
                    const int base = 16 * half;
                    uint32_t c0, c1, c2, c3;
                    asm("v_cvt_pk_bf16_f32 %0, %1, %2" : "=v"(c0) : "v"(pv[base + 0]), "v"(pv[base + 1]));
                    asm("v_cvt_pk_bf16_f32 %0, %1, %2" : "=v"(c1) : "v"(pv[base + 2]), "v"(pv[base + 3]));
                    asm("v_cvt_pk_bf16_f32 %0, %1, %2" : "=v"(c2) : "v"(pv[base + 4]), "v"(pv[base + 5]));
                    asm("v_cvt_pk_bf16_f32 %0, %1, %2" : "=v"(c3) : "v"(pv[base + 6]), "v"(pv[base + 7]));
                    asm volatile("v_permlane32_swap_b32 %0, %1" : "+v"(c0), "+v"(c2));
                    asm volatile("v_permlane32_swap_b32 %0, %1" : "+v"(c1), "+v"(c3));
                    uint32_t w4[4] = {c0, c1, c2, c3};
                    pb[2 * half] = *(bf16x8*)w4;
                    uint32_t d0, d1, d2, d3;
                    asm("v_cvt_pk_bf16_f32 %0, %1, %2" : "=v"(d0) : "v"(pv[base + 8]),  "v"(pv[base + 9]));
                    asm("v_cvt_pk_bf16_f32 %0, %1, %2" : "=v"(d1) : "v"(pv[base + 10]), "v"(pv[base + 11]));
                    asm("v_cvt_pk_bf16_f32 %0, %1, %2" : "=v"(d2) : "v"(pv[base + 12]), "v"(pv[base + 13]));
                    asm("v_cvt_pk_bf16_f32 %0, %1, %2" : "=v"(d3) : "v"(pv[base + 14]), "v"(pv[base + 15]));
                    asm volatile("v_permlane32_swap_b32 %0, %1" : "+v"(d0), "+v"(d2));
                    asm volatile("v_permlane32_swap_b32 %0, %1" : "+v"(d1), "+v"(d3));
                    uint32_t w5[4] = {d0, d1, d2, d3};
                    pb[2 * half + 1] = *(bf16x8*)w5;
                }

                // ---- PV (swapped): O^T[d][q] += V^T[d][kv] @ P^T[kv][q] ----
                __builtin_amdgcn_s_setprio(1);
                #pragma unroll
                for (int dt = 0; dt < 2; dt++) {
                    int drow = dt * 32 + l31;
                    #pragma unroll
                    for (int ks = 0; ks < 4; ks++) {
                        int cc = (2 * ks + hi) ^ swzr;
                        bf16x8 va = *(const bf16x8*)&Vsm[cur][(size_t)drow * 64 + cc * 8];
                        oacc[dt] = __builtin_amdgcn_mfma_f32_32x32x16_bf16(va, pb[ks], oacc[dt], 0, 0, 0);
                    }
                }
                __builtin_amdgcn_s_setprio(0);
            }
            __syncthreads();
        }

        // ---- epilogue for this task ----
        float inv = 1.0f / l_run;
        int b = bh >> 4, h = bh & 15;
        u16t* Op = Ob + ((size_t)(b * Ss + qlane)) * Dd + h * 64;
        #pragma unroll
        for (int dt = 0; dt < 2; dt++)
            #pragma unroll
            for (int rq = 0; rq < 4; rq++) {
                u16t pk4[4];
                #pragma unroll
                for (int j = 0; j < 4; j++) pk4[j] = f2bf(oacc[dt][rq * 4 + j] * inv);
                int d0 = dt * 32 + rq * 8 + hi * 4;
                *(ushort4*)(Op + d0) = *(ushort4*)pk4;
            }
    }
}

extern "C" void kernel_launch(void* const* d_in, const int* in_sizes, int n_in,
                              void* d_out, int out_size, void* d_ws, size_t ws_size,
                              hipStream_t stream) {
    const float* x  = (const float*)d_in[0];
    const float* Wq = (const float*)d_in[1];
    const float* bq = (const float*)d_in[2];
    const float* Wk = (const float*)d_in[3];
    const float* bk = (const float*)d_in[4];
    const float* Wv = (const float*)d_in[5];
    const float* bv = (const float*)d_in[6];
    const float* Wo = (const float*)d_in[7];
    const float* bo = (const float*)d_in[8];

    char* ws = (char*)d_ws;
    size_t off = 0;
    auto alloc = [&](size_t bytes) { char* p = ws + off; off += (bytes + 255) & ~(size_t)255; return p; };
    u16t* xb    = (u16t*)alloc((size_t)Mrows * Dd * 2);
    u16t* WqkvT = (u16t*)alloc((size_t)3 * Dd * Dd * 2);
    u16t* WoT   = (u16t*)alloc((size_t)Dd * Dd * 2);
    u16t* Qh    = (u16t*)alloc((size_t)Mrows * Dd * 2);
    u16t* Kh    = (u16t*)alloc((size_t)Mrows * Dd * 2);
    u16t* Vtp   = (u16t*)alloc((size_t)Mrows * Dd * 2);
    u16t* Ob    = (u16t*)alloc((size_t)Mrows * Dd * 2);

    int nx = Mrows * Dd;
    cvt_bf16<<<nx / (256 * 4), 256, 0, stream>>>(x, xb, nx);
    dim3 tg(16, 16, 4);
    transpose_cvt4<<<tg, 256, 0, stream>>>(Wq, Wk, Wv, Wo, WqkvT, WoT);

    gemm_qkv<<<1536, 256, 0, stream>>>(xb, WqkvT, bq, bk, bv, Qh, Kh, Vtp);

    dim3 ga(8, Bb * Hh);              // 512 uniform blocks
    attn<<<ga, 256, 0, stream>>>(Qh, Kh, Vtp, Ob);

    gemm_o<<<512, 256, 0, stream>>>(Ob, WoT, bo, (float*)d_out);
}